// Round 2
// baseline (2994.616 us; speedup 1.0000x reference)
//
#include <hip/hip_runtime.h>
#include <hip/hip_bf16.h>
#include <cstdint>
#include <cstddef>

// Problem dims (compile-time)
constexpr int Bc = 8;
constexpr int Vc = 2048;   // S*T
constexpr int Pc = 512;
constexpr int Nc = 64;     // 2*S neighbors
constexpr int Ic = 256;
constexpr int Hc = 8;
constexpr int ADc = 32;
constexpr int Dc = 256;    // H*AD
constexpr int Mc = 256;
constexpr int Lc = 2;
constexpr int Rc = 128;
constexpr int ROWS_KV = Bc * Vc;   // 16384
constexpr int ROWS_AT = Bc * Pc;   // 4096

// ---------------------------------------------------------------------------
// Fused 3-layer KV MLP: per block = 32 points x one (l,h) x one of {k,v}.
//   h1 = relu(merged @ W1 + b1)   K=257 (256 encoded + 1 true_u)
//   h2 = relu(h1 @ W2 + b2)       K=256
//   out = h2 @ W3 + b3            K=256, 32 cols
// LDS: bufA holds h1 (32x256), bufB holds X-chunk (stage1) then h2.
// Thread micro-tile: 8 rows x 4 cols (c0=tid&63, cols {c0,+64,+128,+192}).
// X reads from LDS are wave-uniform broadcasts (rg=tid>>6 constant per wave).
// ---------------------------------------------------------------------------
__global__ __launch_bounds__(256) void kv_mlp_kernel(
    const float* __restrict__ encoded, const float* __restrict__ true_u,
    const float* __restrict__ W1k, const float* __restrict__ b1k,
    const float* __restrict__ W2k, const float* __restrict__ b2k,
    const float* __restrict__ W3k, const float* __restrict__ b3k,
    const float* __restrict__ W1v, const float* __restrict__ b1v,
    const float* __restrict__ W2v, const float* __restrict__ b2v,
    const float* __restrict__ W3v, const float* __restrict__ b3v,
    float* __restrict__ keys, float* __restrict__ vals)
{
    __shared__ float bufA[32 * 256];   // h1
    __shared__ float bufB[32 * 256];   // X chunk (stride 68) then h2

    const int tid = threadIdx.x;
    const int lh  = blockIdx.y;        // l*8 + h
    const bool isv = (blockIdx.z != 0);

    const float* W1 = (isv ? W1v : W1k) + (size_t)lh * 257 * 256;
    const float* b1 = (isv ? b1v : b1k) + lh * 256;
    const float* W2 = (isv ? W2v : W2k) + (size_t)lh * 256 * 256;
    const float* b2 = (isv ? b2v : b2k) + lh * 256;
    const float* W3 = (isv ? W3v : W3k) + (size_t)lh * 256 * 32;
    const float* b3 = (isv ? b3v : b3k) + lh * 32;
    float* outp = isv ? vals : keys;

    const int row0 = blockIdx.x * 32;  // flat (b*V+v) row base
    const int c0 = tid & 63;
    const int rg = tid >> 6;           // wave id 0..3 -> rows rg*8..rg*8+7

    float acc[8][4];

    // ---------------- stage 1 ----------------
    {
        float bv0 = b1[c0], bv1 = b1[c0 + 64], bv2 = b1[c0 + 128], bv3 = b1[c0 + 192];
        #pragma unroll
        for (int r = 0; r < 8; ++r) { acc[r][0] = bv0; acc[r][1] = bv1; acc[r][2] = bv2; acc[r][3] = bv3; }
    }
    float* Xl = bufB;  // row stride 68 floats
    for (int k0 = 0; k0 < 256; k0 += 64) {
        const int lr = tid >> 4, lq = tid & 15;
        *(float4*)&Xl[lr * 68 + lq * 4] =
            *(const float4*)&encoded[(size_t)(row0 + lr) * 256 + k0 + lq * 4];
        *(float4*)&Xl[(lr + 16) * 68 + lq * 4] =
            *(const float4*)&encoded[(size_t)(row0 + lr + 16) * 256 + k0 + lq * 4];
        __syncthreads();
        const float* Wb = W1 + (size_t)k0 * 256;
        #pragma unroll 2
        for (int kk = 0; kk < 64; kk += 4) {
            float w[4][4];
            #pragma unroll
            for (int ks = 0; ks < 4; ++ks) {
                const float* wr = Wb + (size_t)(kk + ks) * 256 + c0;
                w[ks][0] = wr[0]; w[ks][1] = wr[64]; w[ks][2] = wr[128]; w[ks][3] = wr[192];
            }
            #pragma unroll
            for (int r = 0; r < 8; ++r) {
                float4 x4 = *(const float4*)&Xl[(rg * 8 + r) * 68 + kk];
                acc[r][0] += x4.x * w[0][0] + x4.y * w[1][0] + x4.z * w[2][0] + x4.w * w[3][0];
                acc[r][1] += x4.x * w[0][1] + x4.y * w[1][1] + x4.z * w[2][1] + x4.w * w[3][1];
                acc[r][2] += x4.x * w[0][2] + x4.y * w[1][2] + x4.z * w[2][2] + x4.w * w[3][2];
                acc[r][3] += x4.x * w[0][3] + x4.y * w[1][3] + x4.z * w[2][3] + x4.w * w[3][3];
            }
        }
        __syncthreads();
    }
    {   // k = 256 term: x = true_u[row]
        const float* wr = W1 + (size_t)256 * 256 + c0;
        float w0 = wr[0], w1 = wr[64], w2 = wr[128], w3 = wr[192];
        #pragma unroll
        for (int r = 0; r < 8; ++r) {
            float x = true_u[row0 + rg * 8 + r];
            acc[r][0] += x * w0; acc[r][1] += x * w1; acc[r][2] += x * w2; acc[r][3] += x * w3;
        }
    }
    #pragma unroll
    for (int r = 0; r < 8; ++r) {
        float* hr = bufA + (rg * 8 + r) * 256 + c0;
        hr[0]   = fmaxf(acc[r][0], 0.f);
        hr[64]  = fmaxf(acc[r][1], 0.f);
        hr[128] = fmaxf(acc[r][2], 0.f);
        hr[192] = fmaxf(acc[r][3], 0.f);
    }
    __syncthreads();

    // ---------------- stage 2 ----------------
    {
        float bv0 = b2[c0], bv1 = b2[c0 + 64], bv2 = b2[c0 + 128], bv3 = b2[c0 + 192];
        #pragma unroll
        for (int r = 0; r < 8; ++r) { acc[r][0] = bv0; acc[r][1] = bv1; acc[r][2] = bv2; acc[r][3] = bv3; }
    }
    #pragma unroll 2
    for (int kk = 0; kk < 256; kk += 4) {
        float w[4][4];
        #pragma unroll
        for (int ks = 0; ks < 4; ++ks) {
            const float* wr = W2 + (size_t)(kk + ks) * 256 + c0;
            w[ks][0] = wr[0]; w[ks][1] = wr[64]; w[ks][2] = wr[128]; w[ks][3] = wr[192];
        }
        #pragma unroll
        for (int r = 0; r < 8; ++r) {
            float4 x4 = *(const float4*)&bufA[(rg * 8 + r) * 256 + kk];
            acc[r][0] += x4.x * w[0][0] + x4.y * w[1][0] + x4.z * w[2][0] + x4.w * w[3][0];
            acc[r][1] += x4.x * w[0][1] + x4.y * w[1][1] + x4.z * w[2][1] + x4.w * w[3][1];
            acc[r][2] += x4.x * w[0][2] + x4.y * w[1][2] + x4.z * w[2][2] + x4.w * w[3][2];
            acc[r][3] += x4.x * w[0][3] + x4.y * w[1][3] + x4.z * w[2][3] + x4.w * w[3][3];
        }
    }
    #pragma unroll
    for (int r = 0; r < 8; ++r) {
        float* hr = bufB + (rg * 8 + r) * 256 + c0;
        hr[0]   = fmaxf(acc[r][0], 0.f);
        hr[64]  = fmaxf(acc[r][1], 0.f);
        hr[128] = fmaxf(acc[r][2], 0.f);
        hr[192] = fmaxf(acc[r][3], 0.f);
    }
    __syncthreads();

    // ---------------- stage 3 (32 cols) ----------------
    const int c3 = tid & 31;
    const int rg3 = tid >> 5;  // 0..7 -> rows rg3*4..+3
    float a3[4];
    {
        float bv = b3[c3];
        #pragma unroll
        for (int r = 0; r < 4; ++r) a3[r] = bv;
    }
    for (int kk = 0; kk < 256; kk += 4) {
        float w0 = W3[(size_t)kk * 32 + c3];
        float w1 = W3[(size_t)(kk + 1) * 32 + c3];
        float w2 = W3[(size_t)(kk + 2) * 32 + c3];
        float w3 = W3[(size_t)(kk + 3) * 32 + c3];
        #pragma unroll
        for (int r = 0; r < 4; ++r) {
            float4 x4 = *(const float4*)&bufB[(rg3 * 4 + r) * 256 + kk];
            a3[r] += x4.x * w0 + x4.y * w1 + x4.z * w2 + x4.w * w3;
        }
    }
    const int l_ = lh >> 3, h_ = lh & 7;
    const int b_ = row0 >> 11;       // row0 / 2048
    const int v0 = row0 & 2047;
    float* op = outp + ((((size_t)l_ * Bc + b_) * Hc + h_) * Vc + v0) * 32;
    #pragma unroll
    for (int r = 0; r < 4; ++r)
        op[(size_t)(rg3 * 4 + r) * 32 + c3] = a3[r];
}

// ---------------------------------------------------------------------------
// Generic GEMM: out[rows x COLS] = act(X[rows x 256] @ W[256 x COLS] + bias)
// 32-row tiles, optional gather of X rows via pred_points (row->b*V+pp[p]).
// ---------------------------------------------------------------------------
template<int COLS, bool RELU, bool GATHER>
__global__ __launch_bounds__(256) void gemm_kernel(
    const float* __restrict__ X, const float* __restrict__ W,
    const float* __restrict__ bias, float* __restrict__ out,
    const int* __restrict__ pp)
{
    __shared__ float Xl[32 * 68];
    constexpr int JJ = COLS / 64;
    const int tid = threadIdx.x;
    const int row0 = blockIdx.x * 32;
    const int c0 = tid & 63;
    const int rg = tid >> 6;

    float acc[8][JJ];
    #pragma unroll
    for (int j = 0; j < JJ; ++j) {
        float bv = bias[c0 + j * 64];
        #pragma unroll
        for (int r = 0; r < 8; ++r) acc[r][j] = bv;
    }

    for (int k0 = 0; k0 < 256; k0 += 64) {
        const int lr = tid >> 4, lq = tid & 15;
        size_t sr0, sr1;
        if (GATHER) {
            int ra = row0 + lr;
            int rb = row0 + lr + 16;
            sr0 = (size_t)(ra >> 9) * Vc + pp[ra & 511];
            sr1 = (size_t)(rb >> 9) * Vc + pp[rb & 511];
        } else {
            sr0 = (size_t)(row0 + lr);
            sr1 = (size_t)(row0 + lr + 16);
        }
        *(float4*)&Xl[lr * 68 + lq * 4]        = *(const float4*)&X[sr0 * 256 + k0 + lq * 4];
        *(float4*)&Xl[(lr + 16) * 68 + lq * 4] = *(const float4*)&X[sr1 * 256 + k0 + lq * 4];
        __syncthreads();
        #pragma unroll 2
        for (int kk = 0; kk < 64; kk += 4) {
            float w[4][JJ];
            #pragma unroll
            for (int ks = 0; ks < 4; ++ks) {
                const float* wr = W + (size_t)(k0 + kk + ks) * COLS + c0;
                #pragma unroll
                for (int j = 0; j < JJ; ++j) w[ks][j] = wr[j * 64];
            }
            #pragma unroll
            for (int r = 0; r < 8; ++r) {
                float4 x4 = *(const float4*)&Xl[(rg * 8 + r) * 68 + kk];
                #pragma unroll
                for (int j = 0; j < JJ; ++j)
                    acc[r][j] += x4.x * w[0][j] + x4.y * w[1][j] + x4.z * w[2][j] + x4.w * w[3][j];
            }
        }
        __syncthreads();
    }
    #pragma unroll
    for (int r = 0; r < 8; ++r)
        #pragma unroll
        for (int j = 0; j < JJ; ++j) {
            float v = acc[r][j];
            if (RELU) v = fmaxf(v, 0.f);
            out[(size_t)(row0 + rg * 8 + r) * COLS + c0 + j * 64] = v;
        }
}

// ---------------------------------------------------------------------------
// Attention for one layer: block = one (b,p); wave h computes 64 scores,
// softmax across the wave, then lanes 0..31 accumulate the weighted values.
// ---------------------------------------------------------------------------
__global__ __launch_bounds__(512) void attn_kernel(
    const float* __restrict__ keys, const float* __restrict__ vals,
    const float* __restrict__ av, const int* __restrict__ nbr,
    const float* __restrict__ mask, float* __restrict__ att, const int l)
{
    __shared__ float qs[256];
    __shared__ float wts[8 * 64];
    __shared__ int ni[64];
    const int row = blockIdx.x;        // b*512 + p
    const int b = row >> 9, p = row & 511;
    const int tid = threadIdx.x;
    const int h = tid >> 6, n = tid & 63;

    if (tid < 256) qs[tid] = av[(size_t)row * 256 + tid];
    if (tid < 64)  ni[tid] = nbr[p * 64 + tid];
    __syncthreads();

    const int vi = ni[n];
    const float* kp = keys + ((((size_t)l * Bc + b) * Hc + h) * Vc + vi) * 32;
    const float* qh = qs + h * 32;
    float s = 0.f;
    #pragma unroll
    for (int d4 = 0; d4 < 8; ++d4) {
        float4 k4 = *(const float4*)&kp[d4 * 4];
        s += qh[d4 * 4 + 0] * k4.x + qh[d4 * 4 + 1] * k4.y +
             qh[d4 * 4 + 2] * k4.z + qh[d4 * 4 + 3] * k4.w;
    }
    s = (s - mask[p * 64 + n]) * 0.17677669529663689f;  // AD^-0.5

    float mx = s;
    #pragma unroll
    for (int off = 32; off >= 1; off >>= 1) mx = fmaxf(mx, __shfl_xor(mx, off));
    float e = expf(s - mx);
    float sum = e;
    #pragma unroll
    for (int off = 32; off >= 1; off >>= 1) sum += __shfl_xor(sum, off);
    wts[h * 64 + n] = e / sum;
    __syncthreads();

    if (n < 32) {
        const int d = n;
        const float* vb = vals + ((((size_t)l * Bc + b) * Hc + h) * Vc) * 32;
        float a = 0.f;
        for (int nn = 0; nn < 64; ++nn)
            a += wts[h * 64 + nn] * vb[(size_t)ni[nn] * 32 + d];
        att[(size_t)row * 256 + h * 32 + d] = a;
    }
}

// ---------------------------------------------------------------------------
// out = LayerNorm(A + Bv) * g + be   (row-wise over 256)
// ---------------------------------------------------------------------------
__global__ __launch_bounds__(256) void add_ln_kernel(
    const float* __restrict__ A, const float* __restrict__ Bv,
    const float* __restrict__ g, const float* __restrict__ be,
    float* __restrict__ outp)
{
    __shared__ float red[4];
    __shared__ float red2[4];
    const int row = blockIdx.x, tid = threadIdx.x;
    float x = A[(size_t)row * 256 + tid] + Bv[(size_t)row * 256 + tid];
    float s = x;
    #pragma unroll
    for (int off = 32; off >= 1; off >>= 1) s += __shfl_xor(s, off);
    if ((tid & 63) == 0) red[tid >> 6] = s;
    __syncthreads();
    float mu = (red[0] + red[1] + red[2] + red[3]) * (1.0f / 256.0f);
    float dx = x - mu;
    float v = dx * dx;
    #pragma unroll
    for (int off = 32; off >= 1; off >>= 1) v += __shfl_xor(v, off);
    if ((tid & 63) == 0) red2[tid >> 6] = v;
    __syncthreads();
    float var = (red2[0] + red2[1] + red2[2] + red2[3]) * (1.0f / 256.0f);
    outp[(size_t)row * 256 + tid] = dx * (1.0f / sqrtf(var + 1e-5f)) * g[tid] + be[tid];
}

// ---------------------------------------------------------------------------
// Loss: per (b,p) row of logits[128]: -(log(128) + log_softmax at target)
// ---------------------------------------------------------------------------
__global__ __launch_bounds__(128) void loss_kernel(
    const float* __restrict__ logits, const float* __restrict__ true_u,
    const int* __restrict__ pp, float* __restrict__ outp)
{
    __shared__ float m2[2];
    __shared__ float s2[2];
    const int row = blockIdx.x;
    const int b = row >> 9, p = row & 511;
    const int tid = threadIdx.x;
    const float x = logits[(size_t)row * 128 + tid];
    float mx = x;
    #pragma unroll
    for (int off = 32; off >= 1; off >>= 1) mx = fmaxf(mx, __shfl_xor(mx, off));
    if ((tid & 63) == 0) m2[tid >> 6] = mx;
    __syncthreads();
    mx = fmaxf(m2[0], m2[1]);
    float e = expf(x - mx);
    float ss = e;
    #pragma unroll
    for (int off = 32; off >= 1; off >>= 1) ss += __shfl_xor(ss, off);
    if ((tid & 63) == 0) s2[tid >> 6] = ss;
    __syncthreads();
    if (tid == 0) {
        float sum = s2[0] + s2[1];
        float tu = true_u[(size_t)b * Vc + pp[p]];
        int t = (int)floorf(tu * 128.0f);
        t = t < 0 ? 0 : (t > 127 ? 127 : t);
        float xt = logits[(size_t)row * 128 + t];
        float lp = logf(128.0f) + (xt - mx) - logf(sum);
        atomicAdd(&outp[b], -lp);
    }
}

// ---------------------------------------------------------------------------
extern "C" void kernel_launch(void* const* d_in, const int* in_sizes, int n_in,
                              void* d_out, int out_size, void* d_ws, size_t ws_size,
                              hipStream_t stream)
{
    (void)in_sizes; (void)n_in; (void)out_size; (void)ws_size;

    const float* encoded        = (const float*)d_in[0];
    const float* true_u         = (const float*)d_in[1];
    const float* attn_mask      = (const float*)d_in[2];
    const int*   pred_points    = (const int*)d_in[3];
    const int*   neighbor_index = (const int*)d_in[4];
    const float* kW1 = (const float*)d_in[5];
    const float* kb1 = (const float*)d_in[6];
    const float* kW2 = (const float*)d_in[7];
    const float* kb2 = (const float*)d_in[8];
    const float* kW3 = (const float*)d_in[9];
    const float* kb3 = (const float*)d_in[10];
    const float* vW1 = (const float*)d_in[11];
    const float* vb1 = (const float*)d_in[12];
    const float* vW2 = (const float*)d_in[13];
    const float* vb2 = (const float*)d_in[14];
    const float* vW3 = (const float*)d_in[15];
    const float* vb3 = (const float*)d_in[16];
    const float* ds_W  = (const float*)d_in[17];
    const float* ds_b  = (const float*)d_in[18];
    const float* ln1_g = (const float*)d_in[19];
    const float* ln1_b = (const float*)d_in[20];
    const float* ff_W1 = (const float*)d_in[21];
    const float* ff_b1 = (const float*)d_in[22];
    const float* ff_W2 = (const float*)d_in[23];
    const float* ff_b2 = (const float*)d_in[24];
    const float* ln2_g = (const float*)d_in[25];
    const float* ln2_b = (const float*)d_in[26];
    const float* de_W1 = (const float*)d_in[27];
    const float* de_b1 = (const float*)d_in[28];
    const float* de_W2 = (const float*)d_in[29];
    const float* de_b2 = (const float*)d_in[30];
    const float* de_W3 = (const float*)d_in[31];
    const float* de_b3 = (const float*)d_in[32];

    float* out = (float*)d_out;

    // workspace layout (floats)
    constexpr size_t KV_ELEMS = (size_t)Lc * Bc * Hc * Vc * ADc;  // 8,388,608
    float* keys = (float*)d_ws;
    float* vals = keys + KV_ELEMS;
    float* AV   = vals + KV_ELEMS;                 // 4096 x 256
    float* ATT  = AV + (size_t)ROWS_AT * 256;
    float* T1   = ATT + (size_t)ROWS_AT * 256;
    float* T2   = T1 + (size_t)ROWS_AT * 256;
    float* LOG  = T2 + (size_t)ROWS_AT * 256;      // 4096 x 128

    (void)hipMemsetAsync(out, 0, Bc * sizeof(float), stream);

    // KV MLPs: 512 row-tiles x 16 (l,h) x {k,v}
    kv_mlp_kernel<<<dim3(ROWS_KV / 32, Lc * Hc, 2), 256, 0, stream>>>(
        encoded, true_u, kW1, kb1, kW2, kb2, kW3, kb3,
        vW1, vb1, vW2, vb2, vW3, vb3, keys, vals);

    // att_value = encoded[:,pred_points,:] @ ds_W + ds_b
    gemm_kernel<256, false, true><<<dim3(ROWS_AT / 32), 256, 0, stream>>>(
        encoded, ds_W, ds_b, AV, pred_points);

    for (int l = 0; l < Lc; ++l) {
        attn_kernel<<<dim3(ROWS_AT), 512, 0, stream>>>(
            keys, vals, AV, neighbor_index, attn_mask, ATT, l);
        add_ln_kernel<<<dim3(ROWS_AT), 256, 0, stream>>>(
            AV, ATT, ln1_g + l * 256, ln1_b + l * 256, AV);
        gemm_kernel<256, true, false><<<dim3(ROWS_AT / 32), 256, 0, stream>>>(
            AV, ff_W1 + (size_t)l * 256 * 256, ff_b1 + l * 256, T1, nullptr);
        gemm_kernel<256, false, false><<<dim3(ROWS_AT / 32), 256, 0, stream>>>(
            T1, ff_W2 + (size_t)l * 256 * 256, ff_b2 + l * 256, T2, nullptr);
        add_ln_kernel<<<dim3(ROWS_AT), 256, 0, stream>>>(
            AV, T2, ln2_g + l * 256, ln2_b + l * 256, AV);
    }

    gemm_kernel<256, true, false><<<dim3(ROWS_AT / 32), 256, 0, stream>>>(
        AV, de_W1, de_b1, T1, nullptr);
    gemm_kernel<256, true, false><<<dim3(ROWS_AT / 32), 256, 0, stream>>>(
        T1, de_W2, de_b2, T2, nullptr);
    gemm_kernel<128, false, false><<<dim3(ROWS_AT / 32), 256, 0, stream>>>(
        T2, de_W3, de_b3, LOG, nullptr);

    loss_kernel<<<dim3(ROWS_AT), 128, 0, stream>>>(LOG, true_u, pred_points, out);
}

// Round 3
// 1834.228 us; speedup vs baseline: 1.6326x; 1.6326x over previous
//
#include <hip/hip_runtime.h>
#include <hip/hip_bf16.h>
#include <cstdint>
#include <cstddef>

// Problem dims (compile-time)
constexpr int Bc = 8;
constexpr int Vc = 2048;   // S*T
constexpr int Pc = 512;
constexpr int Nc = 64;     // 2*S neighbors
constexpr int Ic = 256;
constexpr int Hc = 8;
constexpr int ADc = 32;
constexpr int Dc = 256;    // H*AD
constexpr int Mc = 256;
constexpr int Lc = 2;
constexpr int Rc = 128;
constexpr int ROWS_KV = Bc * Vc;   // 16384
constexpr int ROWS_AT = Bc * Pc;   // 4096

typedef __attribute__((ext_vector_type(8))) short bf16x8;   // 8 bf16 (4 VGPRs)
typedef __attribute__((ext_vector_type(4))) float f32x4;

static __device__ __forceinline__ unsigned short f2bf(float v) {
    __hip_bfloat16 h = __float2bfloat16(v);
    return *(unsigned short*)&h;
}

// ---------------------------------------------------------------------------
// Prep: encoded fp32 -> bf16 (row-major [16384][256])
// ---------------------------------------------------------------------------
__global__ __launch_bounds__(256) void conv_x_kernel(
    const float* __restrict__ x, unsigned short* __restrict__ xb)
{
    const int i = blockIdx.x * 256 + threadIdx.x;   // 1 float4 per thread
    float4 v = ((const float4*)x)[i];
    ushort4 o;
    o.x = f2bf(v.x); o.y = f2bf(v.y); o.z = f2bf(v.z); o.w = f2bf(v.w);
    ((ushort4*)xb)[i] = o;
}

// ---------------------------------------------------------------------------
// Prep: transpose W [K=256 x C] fp32 -> [C x 256] bf16 per net (32 nets).
// net = isv*16 + lh.  grid (C/32, 8, 32), block 256 (32x8).
// ---------------------------------------------------------------------------
__global__ __launch_bounds__(256) void transpose_w_kernel(
    const float* __restrict__ srcK, const float* __restrict__ srcV,
    size_t perNetSrc, int C, size_t perNetDst, unsigned short* __restrict__ dst)
{
    __shared__ float t[32][33];
    const int net = blockIdx.z;
    const float* src = ((net >> 4) ? srcV : srcK) + (size_t)(net & 15) * perNetSrc;
    const int c0 = blockIdx.x * 32, k0 = blockIdx.y * 32;
    const int tx = threadIdx.x & 31, ty = threadIdx.x >> 5;
    #pragma unroll
    for (int i = 0; i < 32; i += 8)
        t[ty + i][tx] = src[(size_t)(k0 + ty + i) * C + (c0 + tx)];
    __syncthreads();
    #pragma unroll
    for (int i = 0; i < 32; i += 8)
        dst[(size_t)net * perNetDst + (size_t)(c0 + ty + i) * 256 + (k0 + tx)] =
            f2bf(t[tx][ty + i]);
}

// ---------------------------------------------------------------------------
// Fused 3-layer KV MLP via bf16 MFMA 16x16x32.
// Block = 64 rows, 4 waves; each WAVE independently owns 16 rows:
//   stage1: h1 = relu(X @ W1[0:256] + tu*W1[256] + b1)   (MFMA + fp32 epilogue)
//   stage2: h2 = relu(h1 @ W2 + b2)
//   stage3: out = h2 @ W3 + b3  (32 cols)
// A-frags: lane holds A[m=ln][k=quad*8+j]; B-frags from W^T [col][k] bf16.
// C/D: col=ln, row=quad*4+reg.  h round-trips through per-wave LDS (pad +8).
// ---------------------------------------------------------------------------
__global__ __launch_bounds__(256) void kv_mfma_kernel(
    const unsigned short* __restrict__ Xbf, const float* __restrict__ true_u,
    const unsigned short* __restrict__ W1t, const unsigned short* __restrict__ W2t,
    const unsigned short* __restrict__ W3t,
    const float* __restrict__ kW1, const float* __restrict__ vW1,
    const float* __restrict__ kb1, const float* __restrict__ kb2, const float* __restrict__ kb3,
    const float* __restrict__ vb1, const float* __restrict__ vb2, const float* __restrict__ vb3,
    float* __restrict__ keys, float* __restrict__ vals)
{
    __shared__ unsigned short hbuf[4][16 * 264];   // per-wave private, 33 KB total
    const int tid = threadIdx.x;
    const int w = tid >> 6, lane = tid & 63;
    const int ln = lane & 15, quad = lane >> 4;
    const int lh = blockIdx.y, isv = blockIdx.z;
    const int net = isv * 16 + lh;
    const float* W1f = (isv ? vW1 : kW1) + (size_t)lh * 257 * 256;
    const float* b1  = (isv ? vb1 : kb1) + lh * 256;
    const float* b2  = (isv ? vb2 : kb2) + lh * 256;
    const float* b3  = (isv ? vb3 : kb3) + lh * 32;
    const unsigned short* w1 = W1t + (size_t)net * 65536;
    const unsigned short* w2 = W2t + (size_t)net * 65536;
    const unsigned short* w3 = W3t + (size_t)net * 8192;
    float* outp = isv ? vals : keys;
    const int row0 = blockIdx.x * 64 + w * 16;

    const f32x4 zero = {0.f, 0.f, 0.f, 0.f};
    bf16x8 a[8];
    f32x4 acc[16];

    // ---- stage 1 ----
    {
        const unsigned short* xp = Xbf + (size_t)(row0 + ln) * 256 + quad * 8;
        #pragma unroll
        for (int ks = 0; ks < 8; ++ks)
            a[ks] = *(const bf16x8*)(xp + ks * 32);
    }
    #pragma unroll
    for (int ct = 0; ct < 16; ++ct) acc[ct] = zero;
    #pragma unroll
    for (int ks = 0; ks < 8; ++ks) {
        #pragma unroll
        for (int ct = 0; ct < 16; ++ct) {
            bf16x8 b = *(const bf16x8*)(w1 + (size_t)(ct * 16 + ln) * 256 + ks * 32 + quad * 8);
            acc[ct] = __builtin_amdgcn_mfma_f32_16x16x32_bf16(a[ks], b, acc[ct], 0, 0, 0);
        }
    }
    float tu[4];
    #pragma unroll
    for (int r = 0; r < 4; ++r) tu[r] = true_u[row0 + quad * 4 + r];
    unsigned short* hb = hbuf[w];
    #pragma unroll
    for (int ct = 0; ct < 16; ++ct) {
        const int col = ct * 16 + ln;
        const float wr = W1f[256 * 256 + col];   // K=257th row, fp32
        const float bb = b1[col];
        #pragma unroll
        for (int r = 0; r < 4; ++r) {
            float v = fmaxf(acc[ct][r] + bb + tu[r] * wr, 0.f);
            hb[(quad * 4 + r) * 264 + col] = f2bf(v);
        }
    }
    __syncthreads();

    // ---- stage 2 ----
    #pragma unroll
    for (int ks = 0; ks < 8; ++ks)
        a[ks] = *(const bf16x8*)&hb[ln * 264 + ks * 32 + quad * 8];
    #pragma unroll
    for (int ct = 0; ct < 16; ++ct) acc[ct] = zero;
    #pragma unroll
    for (int ks = 0; ks < 8; ++ks) {
        #pragma unroll
        for (int ct = 0; ct < 16; ++ct) {
            bf16x8 b = *(const bf16x8*)(w2 + (size_t)(ct * 16 + ln) * 256 + ks * 32 + quad * 8);
            acc[ct] = __builtin_amdgcn_mfma_f32_16x16x32_bf16(a[ks], b, acc[ct], 0, 0, 0);
        }
    }
    #pragma unroll
    for (int ct = 0; ct < 16; ++ct) {
        const int col = ct * 16 + ln;
        const float bb = b2[col];
        #pragma unroll
        for (int r = 0; r < 4; ++r) {
            float v = fmaxf(acc[ct][r] + bb, 0.f);
            hb[(quad * 4 + r) * 264 + col] = f2bf(v);
        }
    }
    __syncthreads();

    // ---- stage 3 (32 cols) ----
    #pragma unroll
    for (int ks = 0; ks < 8; ++ks)
        a[ks] = *(const bf16x8*)&hb[ln * 264 + ks * 32 + quad * 8];
    f32x4 acc3[2];
    acc3[0] = zero; acc3[1] = zero;
    #pragma unroll
    for (int ks = 0; ks < 8; ++ks) {
        #pragma unroll
        for (int ct = 0; ct < 2; ++ct) {
            bf16x8 b = *(const bf16x8*)(w3 + (size_t)(ct * 16 + ln) * 256 + ks * 32 + quad * 8);
            acc3[ct] = __builtin_amdgcn_mfma_f32_16x16x32_bf16(a[ks], b, acc3[ct], 0, 0, 0);
        }
    }
    const int b_ = row0 >> 11;
    const int l_ = lh >> 3, h_ = lh & 7;
    float* ob = outp + ((((size_t)l_ * Bc + b_) * Hc + h_) * Vc) * 32;
    #pragma unroll
    for (int ct = 0; ct < 2; ++ct) {
        const float bb = b3[ct * 16 + ln];
        #pragma unroll
        for (int r = 0; r < 4; ++r) {
            const int grow = row0 + quad * 4 + r;
            ob[(size_t)(grow & 2047) * 32 + ct * 16 + ln] = acc3[ct][r] + bb;
        }
    }
}

// ---------------------------------------------------------------------------
// Generic GEMM: out[rows x COLS] = act(X[rows x 256] @ W[256 x COLS] + bias)
// ---------------------------------------------------------------------------
template<int COLS, bool RELU, bool GATHER>
__global__ __launch_bounds__(256) void gemm_kernel(
    const float* __restrict__ X, const float* __restrict__ W,
    const float* __restrict__ bias, float* __restrict__ out,
    const int* __restrict__ pp)
{
    __shared__ float Xl[32 * 68];
    constexpr int JJ = COLS / 64;
    const int tid = threadIdx.x;
    const int row0 = blockIdx.x * 32;
    const int c0 = tid & 63;
    const int rg = tid >> 6;

    float acc[8][JJ];
    #pragma unroll
    for (int j = 0; j < JJ; ++j) {
        float bv = bias[c0 + j * 64];
        #pragma unroll
        for (int r = 0; r < 8; ++r) acc[r][j] = bv;
    }

    for (int k0 = 0; k0 < 256; k0 += 64) {
        const int lr = tid >> 4, lq = tid & 15;
        size_t sr0, sr1;
        if (GATHER) {
            int ra = row0 + lr;
            int rb = row0 + lr + 16;
            sr0 = (size_t)(ra >> 9) * Vc + pp[ra & 511];
            sr1 = (size_t)(rb >> 9) * Vc + pp[rb & 511];
        } else {
            sr0 = (size_t)(row0 + lr);
            sr1 = (size_t)(row0 + lr + 16);
        }
        *(float4*)&Xl[lr * 68 + lq * 4]        = *(const float4*)&X[sr0 * 256 + k0 + lq * 4];
        *(float4*)&Xl[(lr + 16) * 68 + lq * 4] = *(const float4*)&X[sr1 * 256 + k0 + lq * 4];
        __syncthreads();
        #pragma unroll 2
        for (int kk = 0; kk < 64; kk += 4) {
            float w[4][JJ];
            #pragma unroll
            for (int ks = 0; ks < 4; ++ks) {
                const float* wr = W + (size_t)(k0 + kk + ks) * COLS + c0;
                #pragma unroll
                for (int j = 0; j < JJ; ++j) w[ks][j] = wr[j * 64];
            }
            #pragma unroll
            for (int r = 0; r < 8; ++r) {
                float4 x4 = *(const float4*)&Xl[(rg * 8 + r) * 68 + kk];
                #pragma unroll
                for (int j = 0; j < JJ; ++j)
                    acc[r][j] += x4.x * w[0][j] + x4.y * w[1][j] + x4.z * w[2][j] + x4.w * w[3][j];
            }
        }
        __syncthreads();
    }
    #pragma unroll
    for (int r = 0; r < 8; ++r)
        #pragma unroll
        for (int j = 0; j < JJ; ++j) {
            float v = acc[r][j];
            if (RELU) v = fmaxf(v, 0.f);
            out[(size_t)(row0 + rg * 8 + r) * COLS + c0 + j * 64] = v;
        }
}

// ---------------------------------------------------------------------------
// Attention for one layer
// ---------------------------------------------------------------------------
__global__ __launch_bounds__(512) void attn_kernel(
    const float* __restrict__ keys, const float* __restrict__ vals,
    const float* __restrict__ av, const int* __restrict__ nbr,
    const float* __restrict__ mask, float* __restrict__ att, const int l)
{
    __shared__ float qs[256];
    __shared__ float wts[8 * 64];
    __shared__ int ni[64];
    const int row = blockIdx.x;        // b*512 + p
    const int b = row >> 9, p = row & 511;
    const int tid = threadIdx.x;
    const int h = tid >> 6, n = tid & 63;

    if (tid < 256) qs[tid] = av[(size_t)row * 256 + tid];
    if (tid < 64)  ni[tid] = nbr[p * 64 + tid];
    __syncthreads();

    const int vi = ni[n];
    const float* kp = keys + ((((size_t)l * Bc + b) * Hc + h) * Vc + vi) * 32;
    const float* qh = qs + h * 32;
    float s = 0.f;
    #pragma unroll
    for (int d4 = 0; d4 < 8; ++d4) {
        float4 k4 = *(const float4*)&kp[d4 * 4];
        s += qh[d4 * 4 + 0] * k4.x + qh[d4 * 4 + 1] * k4.y +
             qh[d4 * 4 + 2] * k4.z + qh[d4 * 4 + 3] * k4.w;
    }
    s = (s - mask[p * 64 + n]) * 0.17677669529663689f;  // AD^-0.5

    float mx = s;
    #pragma unroll
    for (int off = 32; off >= 1; off >>= 1) mx = fmaxf(mx, __shfl_xor(mx, off));
    float e = expf(s - mx);
    float sum = e;
    #pragma unroll
    for (int off = 32; off >= 1; off >>= 1) sum += __shfl_xor(sum, off);
    wts[h * 64 + n] = e / sum;
    __syncthreads();

    if (n < 32) {
        const int d = n;
        const float* vb = vals + ((((size_t)l * Bc + b) * Hc + h) * Vc) * 32;
        float a = 0.f;
        for (int nn = 0; nn < 64; ++nn)
            a += wts[h * 64 + nn] * vb[(size_t)ni[nn] * 32 + d];
        att[(size_t)row * 256 + h * 32 + d] = a;
    }
}

// ---------------------------------------------------------------------------
// out = LayerNorm(A + Bv) * g + be   (row-wise over 256)
// ---------------------------------------------------------------------------
__global__ __launch_bounds__(256) void add_ln_kernel(
    const float* __restrict__ A, const float* __restrict__ Bv,
    const float* __restrict__ g, const float* __restrict__ be,
    float* __restrict__ outp)
{
    __shared__ float red[4];
    __shared__ float red2[4];
    const int row = blockIdx.x, tid = threadIdx.x;
    float x = A[(size_t)row * 256 + tid] + Bv[(size_t)row * 256 + tid];
    float s = x;
    #pragma unroll
    for (int off = 32; off >= 1; off >>= 1) s += __shfl_xor(s, off);
    if ((tid & 63) == 0) red[tid >> 6] = s;
    __syncthreads();
    float mu = (red[0] + red[1] + red[2] + red[3]) * (1.0f / 256.0f);
    float dx = x - mu;
    float v = dx * dx;
    #pragma unroll
    for (int off = 32; off >= 1; off >>= 1) v += __shfl_xor(v, off);
    if ((tid & 63) == 0) red2[tid >> 6] = v;
    __syncthreads();
    float var = (red2[0] + red2[1] + red2[2] + red2[3]) * (1.0f / 256.0f);
    outp[(size_t)row * 256 + tid] = dx * (1.0f / sqrtf(var + 1e-5f)) * g[tid] + be[tid];
}

// ---------------------------------------------------------------------------
// Loss: per (b,p) row of logits[128]: -(log(128) + log_softmax at target)
// ---------------------------------------------------------------------------
__global__ __launch_bounds__(128) void loss_kernel(
    const float* __restrict__ logits, const float* __restrict__ true_u,
    const int* __restrict__ pp, float* __restrict__ outp)
{
    __shared__ float m2[2];
    __shared__ float s2[2];
    const int row = blockIdx.x;
    const int b = row >> 9, p = row & 511;
    const int tid = threadIdx.x;
    const float x = logits[(size_t)row * 128 + tid];
    float mx = x;
    #pragma unroll
    for (int off = 32; off >= 1; off >>= 1) mx = fmaxf(mx, __shfl_xor(mx, off));
    if ((tid & 63) == 0) m2[tid >> 6] = mx;
    __syncthreads();
    mx = fmaxf(m2[0], m2[1]);
    float e = expf(x - mx);
    float ss = e;
    #pragma unroll
    for (int off = 32; off >= 1; off >>= 1) ss += __shfl_xor(ss, off);
    if ((tid & 63) == 0) s2[tid >> 6] = ss;
    __syncthreads();
    if (tid == 0) {
        float sum = s2[0] + s2[1];
        float tu = true_u[(size_t)b * Vc + pp[p]];
        int t = (int)floorf(tu * 128.0f);
        t = t < 0 ? 0 : (t > 127 ? 127 : t);
        float xt = logits[(size_t)row * 128 + t];
        float lp = logf(128.0f) + (xt - mx) - logf(sum);
        atomicAdd(&outp[b], -lp);
    }
}

// ---------------------------------------------------------------------------
extern "C" void kernel_launch(void* const* d_in, const int* in_sizes, int n_in,
                              void* d_out, int out_size, void* d_ws, size_t ws_size,
                              hipStream_t stream)
{
    (void)in_sizes; (void)n_in; (void)out_size; (void)ws_size;

    const float* encoded        = (const float*)d_in[0];
    const float* true_u         = (const float*)d_in[1];
    const float* attn_mask      = (const float*)d_in[2];
    const int*   pred_points    = (const int*)d_in[3];
    const int*   neighbor_index = (const int*)d_in[4];
    const float* kW1 = (const float*)d_in[5];
    const float* kb1 = (const float*)d_in[6];
    const float* kW2 = (const float*)d_in[7];
    const float* kb2 = (const float*)d_in[8];
    const float* kW3 = (const float*)d_in[9];
    const float* kb3 = (const float*)d_in[10];
    const float* vW1 = (const float*)d_in[11];
    const float* vb1 = (const float*)d_in[12];
    const float* vW2 = (const float*)d_in[13];
    const float* vb2 = (const float*)d_in[14];
    const float* vW3 = (const float*)d_in[15];
    const float* vb3 = (const float*)d_in[16];
    const float* ds_W  = (const float*)d_in[17];
    const float* ds_b  = (const float*)d_in[18];
    const float* ln1_g = (const float*)d_in[19];
    const float* ln1_b = (const float*)d_in[20];
    const float* ff_W1 = (const float*)d_in[21];
    const float* ff_b1 = (const float*)d_in[22];
    const float* ff_W2 = (const float*)d_in[23];
    const float* ff_b2 = (const float*)d_in[24];
    const float* ln2_g = (const float*)d_in[25];
    const float* ln2_b = (const float*)d_in[26];
    const float* de_W1 = (const float*)d_in[27];
    const float* de_b1 = (const float*)d_in[28];
    const float* de_W2 = (const float*)d_in[29];
    const float* de_b2 = (const float*)d_in[30];
    const float* de_W3 = (const float*)d_in[31];
    const float* de_b3 = (const float*)d_in[32];

    float* out = (float*)d_out;

    // workspace layout
    constexpr size_t KV_ELEMS = (size_t)Lc * Bc * Hc * Vc * ADc;  // 8,388,608
    float* keys = (float*)d_ws;
    float* vals = keys + KV_ELEMS;
    float* AV   = vals + KV_ELEMS;                 // 4096 x 256
    float* ATT  = AV + (size_t)ROWS_AT * 256;
    float* T1   = ATT + (size_t)ROWS_AT * 256;
    float* T2   = T1 + (size_t)ROWS_AT * 256;
    float* LOG  = T2 + (size_t)ROWS_AT * 256;      // 4096 x 128
    unsigned short* Xbf = (unsigned short*)(LOG + (size_t)ROWS_AT * 128);
    unsigned short* W1t = Xbf + (size_t)ROWS_KV * 256;   // 32 nets x [256][256]
    unsigned short* W2t = W1t + (size_t)32 * 65536;
    unsigned short* W3t = W2t + (size_t)32 * 65536;      // 32 nets x [32][256]

    (void)hipMemsetAsync(out, 0, Bc * sizeof(float), stream);

    // prep: bf16 conversions / weight transposes
    conv_x_kernel<<<dim3(ROWS_KV * 256 / 4 / 256), 256, 0, stream>>>(encoded, Xbf);
    transpose_w_kernel<<<dim3(8, 8, 32), 256, 0, stream>>>(kW1, vW1, (size_t)257 * 256, 256, 65536, W1t);
    transpose_w_kernel<<<dim3(8, 8, 32), 256, 0, stream>>>(kW2, vW2, (size_t)256 * 256, 256, 65536, W2t);
    transpose_w_kernel<<<dim3(1, 8, 32), 256, 0, stream>>>(kW3, vW3, (size_t)256 * 32,  32,  8192,  W3t);

    // KV MLPs via MFMA: 256 row-tiles x 16 (l,h) x {k,v}
    kv_mfma_kernel<<<dim3(ROWS_KV / 64, 16, 2), 256, 0, stream>>>(
        Xbf, true_u, W1t, W2t, W3t, kW1, vW1,
        kb1, kb2, kb3, vb1, vb2, vb3, keys, vals);

    // att_value = encoded[:,pred_points,:] @ ds_W + ds_b
    gemm_kernel<256, false, true><<<dim3(ROWS_AT / 32), 256, 0, stream>>>(
        encoded, ds_W, ds_b, AV, pred_points);

    for (int l = 0; l < Lc; ++l) {
        attn_kernel<<<dim3(ROWS_AT), 512, 0, stream>>>(
            keys, vals, AV, neighbor_index, attn_mask, ATT, l);
        add_ln_kernel<<<dim3(ROWS_AT), 256, 0, stream>>>(
            AV, ATT, ln1_g + l * 256, ln1_b + l * 256, AV);
        gemm_kernel<256, true, false><<<dim3(ROWS_AT / 32), 256, 0, stream>>>(
            AV, ff_W1 + (size_t)l * 256 * 256, ff_b1 + l * 256, T1, nullptr);
        gemm_kernel<256, false, false><<<dim3(ROWS_AT / 32), 256, 0, stream>>>(
            T1, ff_W2 + (size_t)l * 256 * 256, ff_b2 + l * 256, T2, nullptr);
        add_ln_kernel<<<dim3(ROWS_AT), 256, 0, stream>>>(
            AV, T2, ln2_g + l * 256, ln2_b + l * 256, AV);
    }

    gemm_kernel<256, true, false><<<dim3(ROWS_AT / 32), 256, 0, stream>>>(
        AV, de_W1, de_b1, T1, nullptr);
    gemm_kernel<256, true, false><<<dim3(ROWS_AT / 32), 256, 0, stream>>>(
        T1, de_W2, de_b2, T2, nullptr);
    gemm_kernel<128, false, false><<<dim3(ROWS_AT / 32), 256, 0, stream>>>(
        T2, de_W3, de_b3, LOG, nullptr);

    loss_kernel<<<dim3(ROWS_AT), 128, 0, stream>>>(LOG, true_u, pred_points, out);
}

// Round 4
// 1171.878 us; speedup vs baseline: 2.5554x; 1.5652x over previous
//
#include <hip/hip_runtime.h>
#include <hip/hip_bf16.h>
#include <cstdint>
#include <cstddef>

// Problem dims (compile-time)
constexpr int Bc = 8;
constexpr int Vc = 2048;   // S*T
constexpr int Pc = 512;
constexpr int Nc = 64;     // 2*S neighbors
constexpr int Ic = 256;
constexpr int Hc = 8;
constexpr int ADc = 32;
constexpr int Dc = 256;    // H*AD
constexpr int Mc = 256;
constexpr int Lc = 2;
constexpr int Rc = 128;
constexpr int ROWS_KV = Bc * Vc;   // 16384
constexpr int ROWS_AT = Bc * Pc;   // 4096

typedef __attribute__((ext_vector_type(8))) short bf16x8;   // 8 bf16 (4 VGPRs)
typedef __attribute__((ext_vector_type(4))) float f32x4;

static __device__ __forceinline__ unsigned short f2bf(float v) {
    __hip_bfloat16 h = __float2bfloat16(v);
    return *(unsigned short*)&h;
}

// ---------------------------------------------------------------------------
// Prep: encoded fp32 -> bf16 (row-major [16384][256])
// ---------------------------------------------------------------------------
__global__ __launch_bounds__(256) void conv_x_kernel(
    const float* __restrict__ x, unsigned short* __restrict__ xb)
{
    const int i = blockIdx.x * 256 + threadIdx.x;   // 1 float4 per thread
    float4 v = ((const float4*)x)[i];
    ushort4 o;
    o.x = f2bf(v.x); o.y = f2bf(v.y); o.z = f2bf(v.z); o.w = f2bf(v.w);
    ((ushort4*)xb)[i] = o;
}

// ---------------------------------------------------------------------------
// Prep: transpose W [K=256 x C] fp32 -> [C x 256] bf16 per net (32 nets).
// net = isv*16 + lh.  grid (C/32, 8, 32), block 256 (32x8).
// ---------------------------------------------------------------------------
__global__ __launch_bounds__(256) void transpose_w_kernel(
    const float* __restrict__ srcK, const float* __restrict__ srcV,
    size_t perNetSrc, int C, size_t perNetDst, unsigned short* __restrict__ dst)
{
    __shared__ float t[32][33];
    const int net = blockIdx.z;
    const float* src = ((net >> 4) ? srcV : srcK) + (size_t)(net & 15) * perNetSrc;
    const int c0 = blockIdx.x * 32, k0 = blockIdx.y * 32;
    const int tx = threadIdx.x & 31, ty = threadIdx.x >> 5;
    #pragma unroll
    for (int i = 0; i < 32; i += 8)
        t[ty + i][tx] = src[(size_t)(k0 + ty + i) * C + (c0 + tx)];
    __syncthreads();
    #pragma unroll
    for (int i = 0; i < 32; i += 8)
        dst[(size_t)net * perNetDst + (size_t)(c0 + ty + i) * 256 + (k0 + tx)] =
            f2bf(t[tx][ty + i]);
}

// ---------------------------------------------------------------------------
// Fused 3-layer KV MLP via bf16 MFMA 16x16x32.
// Block = 64 rows x one net. The 4 waves PARTITION the 256 output columns
// (wave w owns cols w*64..w*64+63): each wave computes 4 row-tiles x 4
// col-tiles (acc[4][4]), so every B-fragment load feeds 4 MFMAs and the
// block reads each weight matrix exactly once (vs 4x in the prior version).
// h1/h2 are exchanged through block-shared LDS (stride 264 shorts: all
// reads/writes <=2-way bank aliasing = free).  3 barriers.
// ---------------------------------------------------------------------------
__global__ __launch_bounds__(256) void kv_mfma_kernel(
    const unsigned short* __restrict__ Xbf, const float* __restrict__ true_u,
    const unsigned short* __restrict__ W1t, const unsigned short* __restrict__ W2t,
    const unsigned short* __restrict__ W3t,
    const float* __restrict__ kW1, const float* __restrict__ vW1,
    const float* __restrict__ kb1, const float* __restrict__ kb2, const float* __restrict__ kb3,
    const float* __restrict__ vb1, const float* __restrict__ vb2, const float* __restrict__ vb3,
    float* __restrict__ keys, float* __restrict__ vals)
{
    __shared__ unsigned short hbuf[64 * 264];   // 33792 B
    const int tid = threadIdx.x;
    const int w = tid >> 6, lane = tid & 63;
    const int ln = lane & 15, quad = lane >> 4;
    const int lh = blockIdx.y, isv = blockIdx.z;
    const int net = isv * 16 + lh;
    const float* W1f = (isv ? vW1 : kW1) + (size_t)lh * 257 * 256;
    const float* b1  = (isv ? vb1 : kb1) + lh * 256;
    const float* b2  = (isv ? vb2 : kb2) + lh * 256;
    const float* b3  = (isv ? vb3 : kb3) + lh * 32;
    const unsigned short* w1 = W1t + (size_t)net * 65536;
    const unsigned short* w2 = W2t + (size_t)net * 65536;
    const unsigned short* w3 = W3t + (size_t)net * 8192;
    float* outp = isv ? vals : keys;
    const int row0 = blockIdx.x * 64;
    const int cb = w * 64;             // this wave's column base (stages 1-2)

    const f32x4 zero = {0.f, 0.f, 0.f, 0.f};
    f32x4 acc[4][4];

    // ---- stage 1: h1 = relu(X @ W1[0:256] + tu*W1[256] + b1) ----
    #pragma unroll
    for (int rt = 0; rt < 4; ++rt)
        #pragma unroll
        for (int ct = 0; ct < 4; ++ct) acc[rt][ct] = zero;
    {
        const unsigned short* xb = Xbf + ((size_t)row0 + ln) * 256 + quad * 8;
        const unsigned short* wb = w1 + (size_t)(cb + ln) * 256 + quad * 8;
        #pragma unroll
        for (int ks = 0; ks < 8; ++ks) {
            bf16x8 A[4], Bv[4];
            #pragma unroll
            for (int rt = 0; rt < 4; ++rt)
                A[rt] = *(const bf16x8*)(xb + (size_t)rt * 16 * 256 + ks * 32);
            #pragma unroll
            for (int ct = 0; ct < 4; ++ct)
                Bv[ct] = *(const bf16x8*)(wb + (size_t)ct * 16 * 256 + ks * 32);
            #pragma unroll
            for (int rt = 0; rt < 4; ++rt)
                #pragma unroll
                for (int ct = 0; ct < 4; ++ct)
                    acc[rt][ct] = __builtin_amdgcn_mfma_f32_16x16x32_bf16(A[rt], Bv[ct], acc[rt][ct], 0, 0, 0);
        }
    }
    // epilogue 1 (fp32): bias + rank-1 true_u term + relu -> hbuf (bf16)
    float tu[4][4];
    #pragma unroll
    for (int rt = 0; rt < 4; ++rt)
        #pragma unroll
        for (int r = 0; r < 4; ++r)
            tu[rt][r] = true_u[row0 + rt * 16 + quad * 4 + r];
    #pragma unroll
    for (int ct = 0; ct < 4; ++ct) {
        const int col = cb + ct * 16 + ln;
        const float wr = W1f[256 * 256 + col];   // K=257th row, fp32
        const float bb = b1[col];
        #pragma unroll
        for (int rt = 0; rt < 4; ++rt)
            #pragma unroll
            for (int r = 0; r < 4; ++r) {
                float v = fmaxf(acc[rt][ct][r] + bb + tu[rt][r] * wr, 0.f);
                hbuf[(rt * 16 + quad * 4 + r) * 264 + col] = f2bf(v);
            }
    }
    __syncthreads();

    // ---- stage 2: h2 = relu(h1 @ W2 + b2) ----
    #pragma unroll
    for (int rt = 0; rt < 4; ++rt)
        #pragma unroll
        for (int ct = 0; ct < 4; ++ct) acc[rt][ct] = zero;
    {
        const unsigned short* wb = w2 + (size_t)(cb + ln) * 256 + quad * 8;
        #pragma unroll
        for (int ks = 0; ks < 8; ++ks) {
            bf16x8 A[4], Bv[4];
            #pragma unroll
            for (int rt = 0; rt < 4; ++rt)
                A[rt] = *(const bf16x8*)&hbuf[(rt * 16 + ln) * 264 + ks * 32 + quad * 8];
            #pragma unroll
            for (int ct = 0; ct < 4; ++ct)
                Bv[ct] = *(const bf16x8*)(wb + (size_t)ct * 16 * 256 + ks * 32);
            #pragma unroll
            for (int rt = 0; rt < 4; ++rt)
                #pragma unroll
                for (int ct = 0; ct < 4; ++ct)
                    acc[rt][ct] = __builtin_amdgcn_mfma_f32_16x16x32_bf16(A[rt], Bv[ct], acc[rt][ct], 0, 0, 0);
        }
    }
    __syncthreads();   // all h1 reads complete before overwrite
    #pragma unroll
    for (int ct = 0; ct < 4; ++ct) {
        const int col = cb + ct * 16 + ln;
        const float bb = b2[col];
        #pragma unroll
        for (int rt = 0; rt < 4; ++rt)
            #pragma unroll
            for (int r = 0; r < 4; ++r) {
                float v = fmaxf(acc[rt][ct][r] + bb, 0.f);
                hbuf[(rt * 16 + quad * 4 + r) * 264 + col] = f2bf(v);
            }
    }
    __syncthreads();

    // ---- stage 3: out = h2 @ W3 + b3 (32 cols); wave w -> rows w*16.. ----
    f32x4 acc3[2];
    acc3[0] = zero; acc3[1] = zero;
    #pragma unroll
    for (int ks = 0; ks < 8; ++ks) {
        bf16x8 A = *(const bf16x8*)&hbuf[(w * 16 + ln) * 264 + ks * 32 + quad * 8];
        #pragma unroll
        for (int ct = 0; ct < 2; ++ct) {
            bf16x8 Bv = *(const bf16x8*)(w3 + (size_t)(ct * 16 + ln) * 256 + ks * 32 + quad * 8);
            acc3[ct] = __builtin_amdgcn_mfma_f32_16x16x32_bf16(A, Bv, acc3[ct], 0, 0, 0);
        }
    }
    const int b_ = row0 >> 11;
    const int l_ = lh >> 3, h_ = lh & 7;
    float* ob = outp + ((((size_t)l_ * Bc + b_) * Hc + h_) * Vc) * 32;
    #pragma unroll
    for (int ct = 0; ct < 2; ++ct) {
        const float bb = b3[ct * 16 + ln];
        #pragma unroll
        for (int r = 0; r < 4; ++r) {
            const int grow = row0 + w * 16 + quad * 4 + r;
            ob[(size_t)(grow & 2047) * 32 + ct * 16 + ln] = acc3[ct][r] + bb;
        }
    }
}

// ---------------------------------------------------------------------------
// Generic GEMM: out[rows x COLS] = act(X[rows x 256] @ W[256 x COLS] + bias)
// ---------------------------------------------------------------------------
template<int COLS, bool RELU, bool GATHER>
__global__ __launch_bounds__(256) void gemm_kernel(
    const float* __restrict__ X, const float* __restrict__ W,
    const float* __restrict__ bias, float* __restrict__ out,
    const int* __restrict__ pp)
{
    __shared__ float Xl[32 * 68];
    constexpr int JJ = COLS / 64;
    const int tid = threadIdx.x;
    const int row0 = blockIdx.x * 32;
    const int c0 = tid & 63;
    const int rg = tid >> 6;

    float acc[8][JJ];
    #pragma unroll
    for (int j = 0; j < JJ; ++j) {
        float bv = bias[c0 + j * 64];
        #pragma unroll
        for (int r = 0; r < 8; ++r) acc[r][j] = bv;
    }

    for (int k0 = 0; k0 < 256; k0 += 64) {
        const int lr = tid >> 4, lq = tid & 15;
        size_t sr0, sr1;
        if (GATHER) {
            int ra = row0 + lr;
            int rb = row0 + lr + 16;
            sr0 = (size_t)(ra >> 9) * Vc + pp[ra & 511];
            sr1 = (size_t)(rb >> 9) * Vc + pp[rb & 511];
        } else {
            sr0 = (size_t)(row0 + lr);
            sr1 = (size_t)(row0 + lr + 16);
        }
        *(float4*)&Xl[lr * 68 + lq * 4]        = *(const float4*)&X[sr0 * 256 + k0 + lq * 4];
        *(float4*)&Xl[(lr + 16) * 68 + lq * 4] = *(const float4*)&X[sr1 * 256 + k0 + lq * 4];
        __syncthreads();
        #pragma unroll 2
        for (int kk = 0; kk < 64; kk += 4) {
            float w[4][JJ];
            #pragma unroll
            for (int ks = 0; ks < 4; ++ks) {
                const float* wr = W + (size_t)(k0 + kk + ks) * COLS + c0;
                #pragma unroll
                for (int j = 0; j < JJ; ++j) w[ks][j] = wr[j * 64];
            }
            #pragma unroll
            for (int r = 0; r < 8; ++r) {
                float4 x4 = *(const float4*)&Xl[(rg * 8 + r) * 68 + kk];
                #pragma unroll
                for (int j = 0; j < JJ; ++j)
                    acc[r][j] += x4.x * w[0][j] + x4.y * w[1][j] + x4.z * w[2][j] + x4.w * w[3][j];
            }
        }
        __syncthreads();
    }
    #pragma unroll
    for (int r = 0; r < 8; ++r)
        #pragma unroll
        for (int j = 0; j < JJ; ++j) {
            float v = acc[r][j];
            if (RELU) v = fmaxf(v, 0.f);
            out[(size_t)(row0 + rg * 8 + r) * COLS + c0 + j * 64] = v;
        }
}

// ---------------------------------------------------------------------------
// Attention for one layer
// ---------------------------------------------------------------------------
__global__ __launch_bounds__(512) void attn_kernel(
    const float* __restrict__ keys, const float* __restrict__ vals,
    const float* __restrict__ av, const int* __restrict__ nbr,
    const float* __restrict__ mask, float* __restrict__ att, const int l)
{
    __shared__ float qs[256];
    __shared__ float wts[8 * 64];
    __shared__ int ni[64];
    const int row = blockIdx.x;        // b*512 + p
    const int b = row >> 9, p = row & 511;
    const int tid = threadIdx.x;
    const int h = tid >> 6, n = tid & 63;

    if (tid < 256) qs[tid] = av[(size_t)row * 256 + tid];
    if (tid < 64)  ni[tid] = nbr[p * 64 + tid];
    __syncthreads();

    const int vi = ni[n];
    const float* kp = keys + ((((size_t)l * Bc + b) * Hc + h) * Vc + vi) * 32;
    const float* qh = qs + h * 32;
    float s = 0.f;
    #pragma unroll
    for (int d4 = 0; d4 < 8; ++d4) {
        float4 k4 = *(const float4*)&kp[d4 * 4];
        s += qh[d4 * 4 + 0] * k4.x + qh[d4 * 4 + 1] * k4.y +
             qh[d4 * 4 + 2] * k4.z + qh[d4 * 4 + 3] * k4.w;
    }
    s = (s - mask[p * 64 + n]) * 0.17677669529663689f;  // AD^-0.5

    float mx = s;
    #pragma unroll
    for (int off = 32; off >= 1; off >>= 1) mx = fmaxf(mx, __shfl_xor(mx, off));
    float e = expf(s - mx);
    float sum = e;
    #pragma unroll
    for (int off = 32; off >= 1; off >>= 1) sum += __shfl_xor(sum, off);
    wts[h * 64 + n] = e / sum;
    __syncthreads();

    if (n < 32) {
        const int d = n;
        const float* vb = vals + ((((size_t)l * Bc + b) * Hc + h) * Vc) * 32;
        float a = 0.f;
        for (int nn = 0; nn < 64; ++nn)
            a += wts[h * 64 + nn] * vb[(size_t)ni[nn] * 32 + d];
        att[(size_t)row * 256 + h * 32 + d] = a;
    }
}

// ---------------------------------------------------------------------------
// out = LayerNorm(A + Bv) * g + be   (row-wise over 256)
// ---------------------------------------------------------------------------
__global__ __launch_bounds__(256) void add_ln_kernel(
    const float* __restrict__ A, const float* __restrict__ Bv,
    const float* __restrict__ g, const float* __restrict__ be,
    float* __restrict__ outp)
{
    __shared__ float red[4];
    __shared__ float red2[4];
    const int row = blockIdx.x, tid = threadIdx.x;
    float x = A[(size_t)row * 256 + tid] + Bv[(size_t)row * 256 + tid];
    float s = x;
    #pragma unroll
    for (int off = 32; off >= 1; off >>= 1) s += __shfl_xor(s, off);
    if ((tid & 63) == 0) red[tid >> 6] = s;
    __syncthreads();
    float mu = (red[0] + red[1] + red[2] + red[3]) * (1.0f / 256.0f);
    float dx = x - mu;
    float v = dx * dx;
    #pragma unroll
    for (int off = 32; off >= 1; off >>= 1) v += __shfl_xor(v, off);
    if ((tid & 63) == 0) red2[tid >> 6] = v;
    __syncthreads();
    float var = (red2[0] + red2[1] + red2[2] + red2[3]) * (1.0f / 256.0f);
    outp[(size_t)row * 256 + tid] = dx * (1.0f / sqrtf(var + 1e-5f)) * g[tid] + be[tid];
}

// ---------------------------------------------------------------------------
// Loss: per (b,p) row of logits[128]: -(log(128) + log_softmax at target)
// ---------------------------------------------------------------------------
__global__ __launch_bounds__(128) void loss_kernel(
    const float* __restrict__ logits, const float* __restrict__ true_u,
    const int* __restrict__ pp, float* __restrict__ outp)
{
    __shared__ float m2[2];
    __shared__ float s2[2];
    const int row = blockIdx.x;
    const int b = row >> 9, p = row & 511;
    const int tid = threadIdx.x;
    const float x = logits[(size_t)row * 128 + tid];
    float mx = x;
    #pragma unroll
    for (int off = 32; off >= 1; off >>= 1) mx = fmaxf(mx, __shfl_xor(mx, off));
    if ((tid & 63) == 0) m2[tid >> 6] = mx;
    __syncthreads();
    mx = fmaxf(m2[0], m2[1]);
    float e = expf(x - mx);
    float ss = e;
    #pragma unroll
    for (int off = 32; off >= 1; off >>= 1) ss += __shfl_xor(ss, off);
    if ((tid & 63) == 0) s2[tid >> 6] = ss;
    __syncthreads();
    if (tid == 0) {
        float sum = s2[0] + s2[1];
        float tu = true_u[(size_t)b * Vc + pp[p]];
        int t = (int)floorf(tu * 128.0f);
        t = t < 0 ? 0 : (t > 127 ? 127 : t);
        float xt = logits[(size_t)row * 128 + t];
        float lp = logf(128.0f) + (xt - mx) - logf(sum);
        atomicAdd(&outp[b], -lp);
    }
}

// ---------------------------------------------------------------------------
extern "C" void kernel_launch(void* const* d_in, const int* in_sizes, int n_in,
                              void* d_out, int out_size, void* d_ws, size_t ws_size,
                              hipStream_t stream)
{
    (void)in_sizes; (void)n_in; (void)out_size; (void)ws_size;

    const float* encoded        = (const float*)d_in[0];
    const float* true_u         = (const float*)d_in[1];
    const float* attn_mask      = (const float*)d_in[2];
    const int*   pred_points    = (const int*)d_in[3];
    const int*   neighbor_index = (const int*)d_in[4];
    const float* kW1 = (const float*)d_in[5];
    const float* kb1 = (const float*)d_in[6];
    const float* kW2 = (const float*)d_in[7];
    const float* kb2 = (const float*)d_in[8];
    const float* kW3 = (const float*)d_in[9];
    const float* kb3 = (const float*)d_in[10];
    const float* vW1 = (const float*)d_in[11];
    const float* vb1 = (const float*)d_in[12];
    const float* vW2 = (const float*)d_in[13];
    const float* vb2 = (const float*)d_in[14];
    const float* vW3 = (const float*)d_in[15];
    const float* vb3 = (const float*)d_in[16];
    const float* ds_W  = (const float*)d_in[17];
    const float* ds_b  = (const float*)d_in[18];
    const float* ln1_g = (const float*)d_in[19];
    const float* ln1_b = (const float*)d_in[20];
    const float* ff_W1 = (const float*)d_in[21];
    const float* ff_b1 = (const float*)d_in[22];
    const float* ff_W2 = (const float*)d_in[23];
    const float* ff_b2 = (const float*)d_in[24];
    const float* ln2_g = (const float*)d_in[25];
    const float* ln2_b = (const float*)d_in[26];
    const float* de_W1 = (const float*)d_in[27];
    const float* de_b1 = (const float*)d_in[28];
    const float* de_W2 = (const float*)d_in[29];
    const float* de_b2 = (const float*)d_in[30];
    const float* de_W3 = (const float*)d_in[31];
    const float* de_b3 = (const float*)d_in[32];

    float* out = (float*)d_out;

    // workspace layout
    constexpr size_t KV_ELEMS = (size_t)Lc * Bc * Hc * Vc * ADc;  // 8,388,608
    float* keys = (float*)d_ws;
    float* vals = keys + KV_ELEMS;
    float* AV   = vals + KV_ELEMS;                 // 4096 x 256
    float* ATT  = AV + (size_t)ROWS_AT * 256;
    float* T1   = ATT + (size_t)ROWS_AT * 256;
    float* T2   = T1 + (size_t)ROWS_AT * 256;
    float* LOG  = T2 + (size_t)ROWS_AT * 256;      // 4096 x 128
    unsigned short* Xbf = (unsigned short*)(LOG + (size_t)ROWS_AT * 128);
    unsigned short* W1t = Xbf + (size_t)ROWS_KV * 256;   // 32 nets x [256][256]
    unsigned short* W2t = W1t + (size_t)32 * 65536;
    unsigned short* W3t = W2t + (size_t)32 * 65536;      // 32 nets x [32][256]

    (void)hipMemsetAsync(out, 0, Bc * sizeof(float), stream);

    // prep: bf16 conversions / weight transposes
    conv_x_kernel<<<dim3(ROWS_KV * 256 / 4 / 256), 256, 0, stream>>>(encoded, Xbf);
    transpose_w_kernel<<<dim3(8, 8, 32), 256, 0, stream>>>(kW1, vW1, (size_t)257 * 256, 256, 65536, W1t);
    transpose_w_kernel<<<dim3(8, 8, 32), 256, 0, stream>>>(kW2, vW2, (size_t)256 * 256, 256, 65536, W2t);
    transpose_w_kernel<<<dim3(1, 8, 32), 256, 0, stream>>>(kW3, vW3, (size_t)256 * 32,  32,  8192,  W3t);

    // KV MLPs via MFMA: 256 row-tiles x 16 (l,h) x {k,v}
    kv_mfma_kernel<<<dim3(ROWS_KV / 64, 16, 2), 256, 0, stream>>>(
        Xbf, true_u, W1t, W2t, W3t, kW1, vW1,
        kb1, kb2, kb3, vb1, vb2, vb3, keys, vals);

    // att_value = encoded[:,pred_points,:] @ ds_W + ds_b
    gemm_kernel<256, false, true><<<dim3(ROWS_AT / 32), 256, 0, stream>>>(
        encoded, ds_W, ds_b, AV, pred_points);

    for (int l = 0; l < Lc; ++l) {
        attn_kernel<<<dim3(ROWS_AT), 512, 0, stream>>>(
            keys, vals, AV, neighbor_index, attn_mask, ATT, l);
        add_ln_kernel<<<dim3(ROWS_AT), 256, 0, stream>>>(
            AV, ATT, ln1_g + l * 256, ln1_b + l * 256, AV);
        gemm_kernel<256, true, false><<<dim3(ROWS_AT / 32), 256, 0, stream>>>(
            AV, ff_W1 + (size_t)l * 256 * 256, ff_b1 + l * 256, T1, nullptr);
        gemm_kernel<256, false, false><<<dim3(ROWS_AT / 32), 256, 0, stream>>>(
            T1, ff_W2 + (size_t)l * 256 * 256, ff_b2 + l * 256, T2, nullptr);
        add_ln_kernel<<<dim3(ROWS_AT), 256, 0, stream>>>(
            AV, T2, ln2_g + l * 256, ln2_b + l * 256, AV);
    }

    gemm_kernel<256, true, false><<<dim3(ROWS_AT / 32), 256, 0, stream>>>(
        AV, de_W1, de_b1, T1, nullptr);
    gemm_kernel<256, true, false><<<dim3(ROWS_AT / 32), 256, 0, stream>>>(
        T1, de_W2, de_b2, T2, nullptr);
    gemm_kernel<128, false, false><<<dim3(ROWS_AT / 32), 256, 0, stream>>>(
        T2, de_W3, de_b3, LOG, nullptr);

    loss_kernel<<<dim3(ROWS_AT), 128, 0, stream>>>(LOG, true_u, pred_points, out);
}

// Round 5
// 884.026 us; speedup vs baseline: 3.3875x; 1.3256x over previous
//
#include <hip/hip_runtime.h>
#include <hip/hip_bf16.h>
#include <cstdint>
#include <cstddef>

// Problem dims (compile-time)
constexpr int Bc = 8;
constexpr int Vc = 2048;   // S*T
constexpr int Pc = 512;
constexpr int Nc = 64;     // 2*S neighbors
constexpr int Hc = 8;
constexpr int ADc = 32;
constexpr int Lc = 2;
constexpr int ROWS_KV = Bc * Vc;   // 16384
constexpr int ROWS_AT = Bc * Pc;   // 4096

typedef __attribute__((ext_vector_type(8))) short bf16x8;   // 8 bf16 (4 VGPRs)
typedef __attribute__((ext_vector_type(4))) float f32x4;

static __device__ __forceinline__ unsigned short f2bf(float v) {
    __hip_bfloat16 h = __float2bfloat16(v);
    return *(unsigned short*)&h;
}

// ---------------------------------------------------------------------------
// Prep: encoded fp32 -> bf16 (row-major [16384][256])
// ---------------------------------------------------------------------------
__global__ __launch_bounds__(256) void conv_x_kernel(
    const float* __restrict__ x, unsigned short* __restrict__ xb)
{
    const int i = blockIdx.x * 256 + threadIdx.x;   // 1 float4 per thread
    float4 v = ((const float4*)x)[i];
    ushort4 o;
    o.x = f2bf(v.x); o.y = f2bf(v.y); o.z = f2bf(v.z); o.w = f2bf(v.w);
    ((ushort4*)xb)[i] = o;
}

// ---------------------------------------------------------------------------
// Prep: transpose W [K=256 x C] fp32 -> [C x 256] bf16 per net (32 nets).
// ---------------------------------------------------------------------------
__global__ __launch_bounds__(256) void transpose_w_kernel(
    const float* __restrict__ srcK, const float* __restrict__ srcV,
    size_t perNetSrc, int C, size_t perNetDst, unsigned short* __restrict__ dst)
{
    __shared__ float t[32][33];
    const int net = blockIdx.z;
    const float* src = ((net >> 4) ? srcV : srcK) + (size_t)(net & 15) * perNetSrc;
    const int c0 = blockIdx.x * 32, k0 = blockIdx.y * 32;
    const int tx = threadIdx.x & 31, ty = threadIdx.x >> 5;
    #pragma unroll
    for (int i = 0; i < 32; i += 8)
        t[ty + i][tx] = src[(size_t)(k0 + ty + i) * C + (c0 + tx)];
    __syncthreads();
    #pragma unroll
    for (int i = 0; i < 32; i += 8)
        dst[(size_t)net * perNetDst + (size_t)(c0 + ty + i) * 256 + (k0 + tx)] =
            f2bf(t[tx][ty + i]);
}

// ---------------------------------------------------------------------------
// Prep: transpose 8 misc matrices [K=256 x C] fp32 -> [C x 256] bf16.
// slot z: 0=ds_W 1=ffW1_0 2=ffW2_0 3=ffW1_1 4=ffW2_1 5=deW1 6=deW2 7=deW3(C=128)
// ---------------------------------------------------------------------------
__global__ __launch_bounds__(256) void transpose_misc_kernel(
    const float* s0, const float* s1, const float* s2, const float* s3,
    const float* s4, const float* s5, const float* s6, const float* s7,
    unsigned short* __restrict__ dst)
{
    const float* srcs[8] = {s0, s1, s2, s3, s4, s5, s6, s7};
    const int id = blockIdx.z;
    const int C = (id == 7) ? 128 : 256;
    if (blockIdx.x * 32 >= C) return;
    __shared__ float t[32][33];
    const float* src = srcs[id];
    const int c0 = blockIdx.x * 32, k0 = blockIdx.y * 32;
    const int tx = threadIdx.x & 31, ty = threadIdx.x >> 5;
    #pragma unroll
    for (int i = 0; i < 32; i += 8)
        t[ty + i][tx] = src[(size_t)(k0 + ty + i) * C + (c0 + tx)];
    __syncthreads();
    #pragma unroll
    for (int i = 0; i < 32; i += 8)
        dst[(size_t)id * 65536 + (size_t)(c0 + ty + i) * 256 + (k0 + tx)] =
            f2bf(t[tx][ty + i]);
}

// h-buf XOR swizzle: 128 rows x 256 shorts (32 chunks of 8 shorts).
// chunk c of row r stored at p = c ^ (r & 31).
static __device__ __forceinline__ int hsw_chunk(int row, int ks, int quad) {
    int c = ks * 4 + quad;
    int p = c ^ (row & 31);
    return row * 256 + p * 8;
}
static __device__ __forceinline__ int hsw_elem(int row, int col) {
    int p = (col >> 3) ^ (row & 31);
    return row * 256 + p * 8 + (col & 7);
}

// ---------------------------------------------------------------------------
// Fused 3-layer KV MLP via bf16 MFMA 16x16x32.  Block = 128 rows x one net.
// 4 waves partition the 256 output cols (stages 1-2); acc[8][4] per wave so
// each K-step is 12 x 16B loads -> 32 MFMAs.  h1/h2 live in a 64KB
// XOR-swizzled LDS buffer (conflict-free frag reads, no pad).
// ---------------------------------------------------------------------------
__global__ __launch_bounds__(256) void kv_mfma_kernel(
    const unsigned short* __restrict__ Xbf, const float* __restrict__ true_u,
    const unsigned short* __restrict__ W1t, const unsigned short* __restrict__ W2t,
    const unsigned short* __restrict__ W3t,
    const float* __restrict__ kW1, const float* __restrict__ vW1,
    const float* __restrict__ kb1, const float* __restrict__ kb2, const float* __restrict__ kb3,
    const float* __restrict__ vb1, const float* __restrict__ vb2, const float* __restrict__ vb3,
    float* __restrict__ keys, float* __restrict__ vals)
{
    __shared__ unsigned short hbuf[128 * 256];   // 65536 B, swizzled
    const int tid = threadIdx.x;
    const int w = tid >> 6, lane = tid & 63;
    const int ln = lane & 15, quad = lane >> 4;
    const int lh = blockIdx.y, isv = blockIdx.z;
    const int net = isv * 16 + lh;
    const float* W1f = (isv ? vW1 : kW1) + (size_t)lh * 257 * 256;
    const float* b1  = (isv ? vb1 : kb1) + lh * 256;
    const float* b2  = (isv ? vb2 : kb2) + lh * 256;
    const float* b3  = (isv ? vb3 : kb3) + lh * 32;
    const unsigned short* w1 = W1t + (size_t)net * 65536;
    const unsigned short* w2 = W2t + (size_t)net * 65536;
    const unsigned short* w3 = W3t + (size_t)net * 8192;
    float* outp = isv ? vals : keys;
    const int row0 = blockIdx.x * 128;
    const int cb = w * 64;             // wave's column base (stages 1-2)

    const f32x4 zero = {0.f, 0.f, 0.f, 0.f};
    f32x4 acc[8][4];

    // ---- stage 1: h1 = relu(X @ W1[0:256] + tu*W1[256] + b1) ----
    #pragma unroll
    for (int rt = 0; rt < 8; ++rt)
        #pragma unroll
        for (int ct = 0; ct < 4; ++ct) acc[rt][ct] = zero;
    {
        const unsigned short* xb = Xbf + ((size_t)row0 + ln) * 256 + quad * 8;
        const unsigned short* wb = w1 + (size_t)(cb + ln) * 256 + quad * 8;
        #pragma unroll
        for (int ks = 0; ks < 8; ++ks) {
            bf16x8 A[8], Bv[4];
            #pragma unroll
            for (int rt = 0; rt < 8; ++rt)
                A[rt] = *(const bf16x8*)(xb + (size_t)rt * 16 * 256 + ks * 32);
            #pragma unroll
            for (int ct = 0; ct < 4; ++ct)
                Bv[ct] = *(const bf16x8*)(wb + (size_t)ct * 16 * 256 + ks * 32);
            #pragma unroll
            for (int rt = 0; rt < 8; ++rt)
                #pragma unroll
                for (int ct = 0; ct < 4; ++ct)
                    acc[rt][ct] = __builtin_amdgcn_mfma_f32_16x16x32_bf16(A[rt], Bv[ct], acc[rt][ct], 0, 0, 0);
        }
    }
    #pragma unroll
    for (int ct = 0; ct < 4; ++ct) {
        const int col = cb + ct * 16 + ln;
        const float wr = W1f[256 * 256 + col];   // K=257th row, fp32
        const float bb = b1[col];
        #pragma unroll
        for (int rt = 0; rt < 8; ++rt)
            #pragma unroll
            for (int r = 0; r < 4; ++r) {
                const int row = rt * 16 + quad * 4 + r;
                float v = fmaxf(acc[rt][ct][r] + bb + true_u[row0 + row] * wr, 0.f);
                hbuf[hsw_elem(row, col)] = f2bf(v);
            }
    }
    __syncthreads();

    // ---- stage 2: h2 = relu(h1 @ W2 + b2) ----
    #pragma unroll
    for (int rt = 0; rt < 8; ++rt)
        #pragma unroll
        for (int ct = 0; ct < 4; ++ct) acc[rt][ct] = zero;
    {
        const unsigned short* wb = w2 + (size_t)(cb + ln) * 256 + quad * 8;
        #pragma unroll
        for (int ks = 0; ks < 8; ++ks) {
            bf16x8 A[8], Bv[4];
            #pragma unroll
            for (int rt = 0; rt < 8; ++rt)
                A[rt] = *(const bf16x8*)&hbuf[hsw_chunk(rt * 16 + ln, ks, quad)];
            #pragma unroll
            for (int ct = 0; ct < 4; ++ct)
                Bv[ct] = *(const bf16x8*)(wb + (size_t)ct * 16 * 256 + ks * 32);
            #pragma unroll
            for (int rt = 0; rt < 8; ++rt)
                #pragma unroll
                for (int ct = 0; ct < 4; ++ct)
                    acc[rt][ct] = __builtin_amdgcn_mfma_f32_16x16x32_bf16(A[rt], Bv[ct], acc[rt][ct], 0, 0, 0);
        }
    }
    __syncthreads();   // all h1 reads complete before overwrite
    #pragma unroll
    for (int ct = 0; ct < 4; ++ct) {
        const int col = cb + ct * 16 + ln;
        const float bb = b2[col];
        #pragma unroll
        for (int rt = 0; rt < 8; ++rt)
            #pragma unroll
            for (int r = 0; r < 4; ++r) {
                const int row = rt * 16 + quad * 4 + r;
                hbuf[hsw_elem(row, col)] = f2bf(fmaxf(acc[rt][ct][r] + bb, 0.f));
            }
    }
    __syncthreads();

    // ---- stage 3: out = h2 @ W3 + b3 (32 cols); wave w -> rows w*32..+31 ----
    f32x4 acc3[2][2];
    acc3[0][0] = zero; acc3[0][1] = zero; acc3[1][0] = zero; acc3[1][1] = zero;
    #pragma unroll
    for (int ks = 0; ks < 8; ++ks) {
        bf16x8 A[2];
        #pragma unroll
        for (int rt = 0; rt < 2; ++rt)
            A[rt] = *(const bf16x8*)&hbuf[hsw_chunk(w * 32 + rt * 16 + ln, ks, quad)];
        #pragma unroll
        for (int ct = 0; ct < 2; ++ct) {
            bf16x8 Bv = *(const bf16x8*)(w3 + (size_t)(ct * 16 + ln) * 256 + ks * 32 + quad * 8);
            #pragma unroll
            for (int rt = 0; rt < 2; ++rt)
                acc3[rt][ct] = __builtin_amdgcn_mfma_f32_16x16x32_bf16(A[rt], Bv, acc3[rt][ct], 0, 0, 0);
        }
    }
    const int b_ = row0 >> 11;
    const int l_ = lh >> 3, h_ = lh & 7;
    float* ob = outp + ((((size_t)l_ * Bc + b_) * Hc + h_) * Vc) * 32;
    #pragma unroll
    for (int ct = 0; ct < 2; ++ct) {
        const float bb = b3[ct * 16 + ln];
        #pragma unroll
        for (int rt = 0; rt < 2; ++rt)
            #pragma unroll
            for (int r = 0; r < 4; ++r) {
                const int grow = row0 + w * 32 + rt * 16 + quad * 4 + r;
                ob[(size_t)(grow & 2047) * 32 + ct * 16 + ln] = acc3[rt][ct][r] + bb;
            }
    }
}

// ---------------------------------------------------------------------------
// Single-stage MFMA GEMM: out[4096 x COLS] = act(A[4096 x 256] @ Wt^T + bias)
// A bf16 (optional row gather), Wt = [COLS][256] bf16.  Block = 64 rows,
// 4 waves partition cols.  Output fp32 or bf16.
// ---------------------------------------------------------------------------
template<int COLS, bool RELU, bool GATHER, bool OUTBF>
__global__ __launch_bounds__(256) void gemm_mfma_kernel(
    const unsigned short* __restrict__ Abf, const unsigned short* __restrict__ Wt,
    const float* __restrict__ bias, float* __restrict__ outF,
    unsigned short* __restrict__ outB, const int* __restrict__ pp)
{
    constexpr int CPW = COLS / 4;        // cols per wave
    constexpr int CT = CPW / 16;         // col tiles per wave
    const int tid = threadIdx.x;
    const int w = tid >> 6, lane = tid & 63;
    const int ln = lane & 15, quad = lane >> 4;
    const int row0 = blockIdx.x * 64;
    const int cb = w * CPW;

    const f32x4 zero = {0.f, 0.f, 0.f, 0.f};
    f32x4 acc[4][CT];
    #pragma unroll
    for (int rt = 0; rt < 4; ++rt)
        #pragma unroll
        for (int ct = 0; ct < CT; ++ct) acc[rt][ct] = zero;

    size_t arow[4];
    #pragma unroll
    for (int rt = 0; rt < 4; ++rt) {
        int ra = row0 + rt * 16 + ln;
        arow[rt] = GATHER ? ((size_t)(ra >> 9) * Vc + pp[ra & 511]) : (size_t)ra;
    }
    const unsigned short* wb = Wt + (size_t)(cb + ln) * 256 + quad * 8;
    #pragma unroll
    for (int ks = 0; ks < 8; ++ks) {
        bf16x8 A[4], Bv[CT];
        #pragma unroll
        for (int rt = 0; rt < 4; ++rt)
            A[rt] = *(const bf16x8*)(Abf + arow[rt] * 256 + ks * 32 + quad * 8);
        #pragma unroll
        for (int ct = 0; ct < CT; ++ct)
            Bv[ct] = *(const bf16x8*)(wb + (size_t)ct * 16 * 256 + ks * 32);
        #pragma unroll
        for (int rt = 0; rt < 4; ++rt)
            #pragma unroll
            for (int ct = 0; ct < CT; ++ct)
                acc[rt][ct] = __builtin_amdgcn_mfma_f32_16x16x32_bf16(A[rt], Bv[ct], acc[rt][ct], 0, 0, 0);
    }
    #pragma unroll
    for (int ct = 0; ct < CT; ++ct) {
        const int col = cb + ct * 16 + ln;
        const float bb = bias[col];
        #pragma unroll
        for (int rt = 0; rt < 4; ++rt)
            #pragma unroll
            for (int r = 0; r < 4; ++r) {
                float v = acc[rt][ct][r] + bb;
                if (RELU) v = fmaxf(v, 0.f);
                const size_t idx = (size_t)(row0 + rt * 16 + quad * 4 + r) * COLS + col;
                if (OUTBF) outB[idx] = f2bf(v);
                else       outF[idx] = v;
            }
    }
}

// ---------------------------------------------------------------------------
// Attention for one layer
// ---------------------------------------------------------------------------
__global__ __launch_bounds__(512) void attn_kernel(
    const float* __restrict__ keys, const float* __restrict__ vals,
    const float* __restrict__ av, const int* __restrict__ nbr,
    const float* __restrict__ mask, float* __restrict__ att, const int l)
{
    __shared__ float qs[256];
    __shared__ float wts[8 * 64];
    __shared__ int ni[64];
    const int row = blockIdx.x;        // b*512 + p
    const int b = row >> 9, p = row & 511;
    const int tid = threadIdx.x;
    const int h = tid >> 6, n = tid & 63;

    if (tid < 256) qs[tid] = av[(size_t)row * 256 + tid];
    if (tid < 64)  ni[tid] = nbr[p * 64 + tid];
    __syncthreads();

    const int vi = ni[n];
    const float* kp = keys + ((((size_t)l * Bc + b) * Hc + h) * Vc + vi) * 32;
    const float* qh = qs + h * 32;
    float s = 0.f;
    #pragma unroll
    for (int d4 = 0; d4 < 8; ++d4) {
        float4 k4 = *(const float4*)&kp[d4 * 4];
        s += qh[d4 * 4 + 0] * k4.x + qh[d4 * 4 + 1] * k4.y +
             qh[d4 * 4 + 2] * k4.z + qh[d4 * 4 + 3] * k4.w;
    }
    s = (s - mask[p * 64 + n]) * 0.17677669529663689f;  // AD^-0.5

    float mx = s;
    #pragma unroll
    for (int off = 32; off >= 1; off >>= 1) mx = fmaxf(mx, __shfl_xor(mx, off));
    float e = expf(s - mx);
    float sum = e;
    #pragma unroll
    for (int off = 32; off >= 1; off >>= 1) sum += __shfl_xor(sum, off);
    wts[h * 64 + n] = e / sum;
    __syncthreads();

    if (n < 32) {
        const int d = n;
        const float* vb = vals + ((((size_t)l * Bc + b) * Hc + h) * Vc) * 32;
        float a = 0.f;
        for (int nn = 0; nn < 64; ++nn)
            a += wts[h * 64 + nn] * vb[(size_t)ni[nn] * 32 + d];
        att[(size_t)row * 256 + h * 32 + d] = a;
    }
}

// ---------------------------------------------------------------------------
// out = LayerNorm(A + Bv) * g + be   (row-wise over 256); fp32 + bf16 copies
// ---------------------------------------------------------------------------
__global__ __launch_bounds__(256) void add_ln_kernel(
    const float* __restrict__ A, const float* __restrict__ Bv,
    const float* __restrict__ g, const float* __restrict__ be,
    float* __restrict__ outF, unsigned short* __restrict__ outB)
{
    __shared__ float red[4];
    __shared__ float red2[4];
    const int row = blockIdx.x, tid = threadIdx.x;
    float x = A[(size_t)row * 256 + tid] + Bv[(size_t)row * 256 + tid];
    float s = x;
    #pragma unroll
    for (int off = 32; off >= 1; off >>= 1) s += __shfl_xor(s, off);
    if ((tid & 63) == 0) red[tid >> 6] = s;
    __syncthreads();
    float mu = (red[0] + red[1] + red[2] + red[3]) * (1.0f / 256.0f);
    float dx = x - mu;
    float v = dx * dx;
    #pragma unroll
    for (int off = 32; off >= 1; off >>= 1) v += __shfl_xor(v, off);
    if ((tid & 63) == 0) red2[tid >> 6] = v;
    __syncthreads();
    float var = (red2[0] + red2[1] + red2[2] + red2[3]) * (1.0f / 256.0f);
    float o = dx * (1.0f / sqrtf(var + 1e-5f)) * g[tid] + be[tid];
    outF[(size_t)row * 256 + tid] = o;
    outB[(size_t)row * 256 + tid] = f2bf(o);
}

// ---------------------------------------------------------------------------
// Loss: per (b,p) row of logits[128]: -(log(128) + log_softmax at target)
// ---------------------------------------------------------------------------
__global__ __launch_bounds__(128) void loss_kernel(
    const float* __restrict__ logits, const float* __restrict__ true_u,
    const int* __restrict__ pp, float* __restrict__ outp)
{
    __shared__ float m2[2];
    __shared__ float s2[2];
    const int row = blockIdx.x;
    const int b = row >> 9, p = row & 511;
    const int tid = threadIdx.x;
    const float x = logits[(size_t)row * 128 + tid];
    float mx = x;
    #pragma unroll
    for (int off = 32; off >= 1; off >>= 1) mx = fmaxf(mx, __shfl_xor(mx, off));
    if ((tid & 63) == 0) m2[tid >> 6] = mx;
    __syncthreads();
    mx = fmaxf(m2[0], m2[1]);
    float e = expf(x - mx);
    float ss = e;
    #pragma unroll
    for (int off = 32; off >= 1; off >>= 1) ss += __shfl_xor(ss, off);
    if ((tid & 63) == 0) s2[tid >> 6] = ss;
    __syncthreads();
    if (tid == 0) {
        float sum = s2[0] + s2[1];
        float tu = true_u[(size_t)b * Vc + pp[p]];
        int t = (int)floorf(tu * 128.0f);
        t = t < 0 ? 0 : (t > 127 ? 127 : t);
        float xt = logits[(size_t)row * 128 + t];
        float lp = logf(128.0f) + (xt - mx) - logf(sum);
        atomicAdd(&outp[b], -lp);
    }
}

// ---------------------------------------------------------------------------
extern "C" void kernel_launch(void* const* d_in, const int* in_sizes, int n_in,
                              void* d_out, int out_size, void* d_ws, size_t ws_size,
                              hipStream_t stream)
{
    (void)in_sizes; (void)n_in; (void)out_size; (void)ws_size;

    const float* encoded        = (const float*)d_in[0];
    const float* true_u         = (const float*)d_in[1];
    const float* attn_mask      = (const float*)d_in[2];
    const int*   pred_points    = (const int*)d_in[3];
    const int*   neighbor_index = (const int*)d_in[4];
    const float* kW1 = (const float*)d_in[5];
    const float* kb1 = (const float*)d_in[6];
    const float* kW2 = (const float*)d_in[7];
    const float* kb2 = (const float*)d_in[8];
    const float* kW3 = (const float*)d_in[9];
    const float* kb3 = (const float*)d_in[10];
    const float* vW1 = (const float*)d_in[11];
    const float* vb1 = (const float*)d_in[12];
    const float* vW2 = (const float*)d_in[13];
    const float* vb2 = (const float*)d_in[14];
    const float* vW3 = (const float*)d_in[15];
    const float* vb3 = (const float*)d_in[16];
    const float* ds_W  = (const float*)d_in[17];
    const float* ds_b  = (const float*)d_in[18];
    const float* ln1_g = (const float*)d_in[19];
    const float* ln1_b = (const float*)d_in[20];
    const float* ff_W1 = (const float*)d_in[21];
    const float* ff_b1 = (const float*)d_in[22];
    const float* ff_W2 = (const float*)d_in[23];
    const float* ff_b2 = (const float*)d_in[24];
    const float* ln2_g = (const float*)d_in[25];
    const float* ln2_b = (const float*)d_in[26];
    const float* de_W1 = (const float*)d_in[27];
    const float* de_b1 = (const float*)d_in[28];
    const float* de_W2 = (const float*)d_in[29];
    const float* de_b2 = (const float*)d_in[30];
    const float* de_W3 = (const float*)d_in[31];
    const float* de_b3 = (const float*)d_in[32];

    float* out = (float*)d_out;

    // workspace layout
    constexpr size_t KV_ELEMS = (size_t)Lc * Bc * Hc * Vc * ADc;  // 8,388,608
    float* keys = (float*)d_ws;
    float* vals = keys + KV_ELEMS;
    float* AV   = vals + KV_ELEMS;                 // 4096 x 256 f32
    float* ATT  = AV + (size_t)ROWS_AT * 256;
    float* T2   = ATT + (size_t)ROWS_AT * 256;
    float* LOG  = T2 + (size_t)ROWS_AT * 256;      // 4096 x 128 f32
    unsigned short* Xbf  = (unsigned short*)(LOG + (size_t)ROWS_AT * 128);
    unsigned short* W1t  = Xbf + (size_t)ROWS_KV * 256;   // 32 nets x [256][256]
    unsigned short* W2t  = W1t + (size_t)32 * 65536;
    unsigned short* W3t  = W2t + (size_t)32 * 65536;      // 32 nets x [32][256]
    unsigned short* Wm   = W3t + (size_t)32 * 8192;       // 8 slots x 65536
    unsigned short* AVbf = Wm + (size_t)8 * 65536;        // 4096 x 256 bf16
    unsigned short* T1bf = AVbf + (size_t)ROWS_AT * 256;
    unsigned short* T2bf = T1bf + (size_t)ROWS_AT * 256;

    (void)hipMemsetAsync(out, 0, Bc * sizeof(float), stream);

    // prep
    conv_x_kernel<<<dim3(ROWS_KV * 256 / 4 / 256), 256, 0, stream>>>(encoded, Xbf);
    transpose_w_kernel<<<dim3(8, 8, 32), 256, 0, stream>>>(kW1, vW1, (size_t)257 * 256, 256, 65536, W1t);
    transpose_w_kernel<<<dim3(8, 8, 32), 256, 0, stream>>>(kW2, vW2, (size_t)256 * 256, 256, 65536, W2t);
    transpose_w_kernel<<<dim3(1, 8, 32), 256, 0, stream>>>(kW3, vW3, (size_t)256 * 32,  32,  8192,  W3t);
    transpose_misc_kernel<<<dim3(8, 8, 8), 256, 0, stream>>>(
        ds_W, ff_W1, ff_W1 + (size_t)65536, ff_W2, ff_W2 + (size_t)65536,
        de_W1, de_W2, de_W3, Wm);
    // NOTE slot order: 0=ds_W 1=ffW1_0 2=ffW1_1 3=ffW2_0 4=ffW2_1 5=deW1 6=deW2 7=deW3

    // KV MLPs via MFMA: 128 row-tiles x 16 (l,h) x {k,v}
    kv_mfma_kernel<<<dim3(ROWS_KV / 128, 16, 2), 256, 0, stream>>>(
        Xbf, true_u, W1t, W2t, W3t, kW1, vW1,
        kb1, kb2, kb3, vb1, vb2, vb3, keys, vals);

    // att_value = encoded[:,pred_points,:] @ ds_W + ds_b  (bf16 A, gathered)
    gemm_mfma_kernel<256, false, true, false><<<dim3(ROWS_AT / 64), 256, 0, stream>>>(
        Xbf, Wm + (size_t)0 * 65536, ds_b, AV, nullptr, pred_points);

    for (int l = 0; l < Lc; ++l) {
        attn_kernel<<<dim3(ROWS_AT), 512, 0, stream>>>(
            keys, vals, AV, neighbor_index, attn_mask, ATT, l);
        add_ln_kernel<<<dim3(ROWS_AT), 256, 0, stream>>>(
            AV, ATT, ln1_g + l * 256, ln1_b + l * 256, AV, AVbf);
        gemm_mfma_kernel<256, true, false, true><<<dim3(ROWS_AT / 64), 256, 0, stream>>>(
            AVbf, Wm + (size_t)(1 + l) * 65536, ff_b1 + l * 256, nullptr, T1bf, nullptr);
        gemm_mfma_kernel<256, false, false, false><<<dim3(ROWS_AT / 64), 256, 0, stream>>>(
            T1bf, Wm + (size_t)(3 + l) * 65536, ff_b2 + l * 256, T2, nullptr, nullptr);
        add_ln_kernel<<<dim3(ROWS_AT), 256, 0, stream>>>(
            AV, T2, ln2_g + l * 256, ln2_b + l * 256, AV, AVbf);
    }

    gemm_mfma_kernel<256, true, false, true><<<dim3(ROWS_AT / 64), 256, 0, stream>>>(
        AVbf, Wm + (size_t)5 * 65536, de_b1, nullptr, T1bf, nullptr);
    gemm_mfma_kernel<256, true, false, true><<<dim3(ROWS_AT / 64), 256, 0, stream>>>(
        T1bf, Wm + (size_t)6 * 65536, de_b2, nullptr, T2bf, nullptr);
    gemm_mfma_kernel<128, false, false, false><<<dim3(ROWS_AT / 64), 256, 0, stream>>>(
        T2bf, Wm + (size_t)7 * 65536, de_b3, LOG, nullptr, nullptr);

    loss_kernel<<<dim3(ROWS_AT), 128, 0, stream>>>(LOG, true_u, pred_points, out);
}